// Round 16
// baseline (562.670 us; speedup 1.0000x reference)
//
#include <hip/hip_runtime.h>
#include <math.h>

#define NB 16
#define SL 32
#define H5 5120
#define K3 3072

typedef __attribute__((ext_vector_type(8))) short short8;
typedef __attribute__((ext_vector_type(4))) float floatx4;
typedef __attribute__((ext_vector_type(4))) int intx4;

__device__ __forceinline__ float sigf(float x) { return 1.0f / (1.0f + expf(-x)); }

__device__ __forceinline__ unsigned short f2bf(float x) {
  union { float f; unsigned int u; } v;
  v.f = x;
  unsigned int r = v.u + 0x7FFFu + ((v.u >> 16) & 1u);
  return (unsigned short)(r >> 16);
}

// ---- barrier variants (hybrid of best-measured per scale) ------------------
// 32-block: direct-poll all-to-all (r12: best for scan, 1 L3 hop).
__device__ __forceinline__ void bar32(int* flags, int idx, int mygen) {
  asm volatile("s_waitcnt vmcnt(0)" ::: "memory");
  __syncthreads();
  const int tid = threadIdx.x;
  if (tid == 0)
    __hip_atomic_store(&flags[idx], mygen, __ATOMIC_RELAXED,
                       __HIP_MEMORY_SCOPE_AGENT);
  if (tid < 64) {
    const int off = (tid & 7) * 4;
    int ok;
    do {
      intx4 f;
      asm volatile("global_load_dwordx4 %0, %1, off sc0 sc1\n\t"
                   "s_waitcnt vmcnt(0)"
                   : "=&v"(f) : "v"(flags + off) : "memory");
      ok = (f.x >= mygen) & (f.y >= mygen) & (f.z >= mygen) & (f.w >= mygen);
    } while (__all(ok) == 0);
  }
  __syncthreads();
}

// 512-block: monitor (r11: best for rounds — single poller avoids 512-way
// poll contention; r12's direct-poll regressed k_rounds).
__device__ __forceinline__ void bar_rounds(int* flags, int* gen, int bid, int mygen) {
  asm volatile("s_waitcnt vmcnt(0)" ::: "memory");
  __syncthreads();
  const int tid = threadIdx.x;
  if (tid < 64) {
    if (tid == 0)
      __hip_atomic_store(&flags[bid], mygen, __ATOMIC_RELAXED,
                         __HIP_MEMORY_SCOPE_AGENT);
    if (bid == 0) {
      int ok;
      do {
        intx4 f0, f1;
        asm volatile("global_load_dwordx4 %0, %2, off sc0 sc1\n\t"
                     "global_load_dwordx4 %1, %3, off sc0 sc1\n\t"
                     "s_waitcnt vmcnt(0)"
                     : "=&v"(f0), "=&v"(f1)
                     : "v"(flags + tid * 8), "v"(flags + tid * 8 + 4)
                     : "memory");
        ok = (f0.x >= mygen) & (f0.y >= mygen) & (f0.z >= mygen) & (f0.w >= mygen)
           & (f1.x >= mygen) & (f1.y >= mygen) & (f1.z >= mygen) & (f1.w >= mygen);
      } while (__all(ok) == 0);
      if (tid == 0)
        __hip_atomic_store(gen, mygen, __ATOMIC_RELAXED,
                           __HIP_MEMORY_SCOPE_AGENT);
    } else if (tid == 0) {
      while (__hip_atomic_load(gen, __ATOMIC_RELAXED,
                               __HIP_MEMORY_SCOPE_AGENT) < mygen)
        __builtin_amdgcn_s_sleep(2);
    }
  }
  __syncthreads();
}

// meta layout (ints):
//  own 0, lt 512, li 1024, rt 1536, ri 2048, dep 2560, nn 3072(16),
//  dcnt 3088(32), lcnt 3120(32), dlist 3152(32*512), llist 19536(32*512)

// ---- E1 gemm body (f32): out[r,g] = sum_k A[r,k]*W[g,k]; lda=512 ldw=513
__device__ void gemm_body(const float* __restrict__ A, const float* __restrict__ W,
                          float* __restrict__ out, int bx, int by)
{
  __shared__ __align__(16) float sm[2 * 16 * 68];
  float* As = sm;
  float* Ws = sm + 16 * 68;
  const int tid = threadIdx.x;
  const int tx = tid & 15, ty = tid >> 4;
  const int g0 = bx * 64, r0 = by * 64;
  float acc[4][4];
#pragma unroll
  for (int i = 0; i < 4; ++i)
#pragma unroll
    for (int j = 0; j < 4; ++j) acc[i][j] = 0.0f;
  const int ks = tid & 15, rr = tid >> 4;
  for (int kt = 0; kt < 512; kt += 16) {
#pragma unroll
    for (int rep = 0; rep < 4; ++rep) {
      As[ks * 68 + rep * 16 + rr] = A[(size_t)(r0 + rep * 16 + rr) * 512 + kt + ks];
      Ws[ks * 68 + rep * 16 + rr] = W[(size_t)(g0 + rep * 16 + rr) * 513 + kt + ks];
    }
    __syncthreads();
#pragma unroll
    for (int k = 0; k < 16; ++k) {
      const float4 a4 = *(const float4*)&As[k * 68 + ty * 4];
      const float4 w4 = *(const float4*)&Ws[k * 68 + tx * 4];
      const float av[4] = {a4.x, a4.y, a4.z, a4.w};
      const float wv[4] = {w4.x, w4.y, w4.z, w4.w};
#pragma unroll
      for (int i = 0; i < 4; ++i)
#pragma unroll
        for (int j = 0; j < 4; ++j) acc[i][j] += av[i] * wv[j];
    }
    __syncthreads();
  }
#pragma unroll
  for (int i = 0; i < 4; ++i) {
    const int r = r0 + ty * 4 + i;
    float4 o;
    o.x = acc[i][0]; o.y = acc[i][1]; o.z = acc[i][2]; o.w = acc[i][3];
    *(float4*)&out[(size_t)r * 256 + g0 + tx * 4] = o;
  }
}

// ---- input projection body: X = emb @ Wih^T, f32 inputs converted inline ---
__device__ void xproj_body(const float* __restrict__ emb,
                           const float* __restrict__ W,
                           float* __restrict__ out, int bx, int by)
{
  __shared__ __align__(16) unsigned short As[128 * 40];
  __shared__ __align__(16) unsigned short Bs[128 * 40];
  const int tid = threadIdx.x;
  const int g0 = bx * 128;
  const int r0 = by * 128;
  const int wave = tid >> 6, lane = tid & 63;
  const int wm = wave >> 1, wn = wave & 1;
  const int l15 = lane & 15, quad = lane >> 4;
  floatx4 acc[4][4];
#pragma unroll
  for (int mt = 0; mt < 4; ++mt)
#pragma unroll
    for (int nt = 0; nt < 4; ++nt) acc[mt][nt] = (floatx4){0.f, 0.f, 0.f, 0.f};
  for (int kt = 0; kt < 512; kt += 32) {
    __syncthreads();
#pragma unroll
    for (int p = 0; p < 2; ++p) {
      const int i = tid + p * 256;
      const int row = i >> 2, q = i & 3;
      const float* pe = &emb[(size_t)(r0 + row) * 512 + kt + q * 8];
      const float* pw = &W[(size_t)(g0 + row) * 512 + kt + q * 8];
      const float4 a0 = *(const float4*)pe;
      const float4 a1 = *(const float4*)(pe + 4);
      const float4 b0 = *(const float4*)pw;
      const float4 b1 = *(const float4*)(pw + 4);
      ushort4 ua0, ua1, ub0, ub1;
      ua0.x = f2bf(a0.x); ua0.y = f2bf(a0.y); ua0.z = f2bf(a0.z); ua0.w = f2bf(a0.w);
      ua1.x = f2bf(a1.x); ua1.y = f2bf(a1.y); ua1.z = f2bf(a1.z); ua1.w = f2bf(a1.w);
      ub0.x = f2bf(b0.x); ub0.y = f2bf(b0.y); ub0.z = f2bf(b0.z); ub0.w = f2bf(b0.w);
      ub1.x = f2bf(b1.x); ub1.y = f2bf(b1.y); ub1.z = f2bf(b1.z); ub1.w = f2bf(b1.w);
      *(ushort4*)&As[row * 40 + q * 8] = ua0;
      *(ushort4*)&As[row * 40 + q * 8 + 4] = ua1;
      *(ushort4*)&Bs[row * 40 + q * 8] = ub0;
      *(ushort4*)&Bs[row * 40 + q * 8 + 4] = ub1;
    }
    __syncthreads();
    short8 af[4], bfr[4];
#pragma unroll
    for (int mt = 0; mt < 4; ++mt)
      af[mt] = *(const short8*)&As[(wm * 64 + mt * 16 + l15) * 40 + quad * 8];
#pragma unroll
    for (int nt = 0; nt < 4; ++nt)
      bfr[nt] = *(const short8*)&Bs[(wn * 64 + nt * 16 + l15) * 40 + quad * 8];
#pragma unroll
    for (int mt = 0; mt < 4; ++mt)
#pragma unroll
      for (int nt = 0; nt < 4; ++nt)
        acc[mt][nt] = __builtin_amdgcn_mfma_f32_16x16x32_bf16(af[mt], bfr[nt], acc[mt][nt], 0, 0, 0);
  }
#pragma unroll
  for (int nt = 0; nt < 4; ++nt) {
    const int col = g0 + wn * 64 + nt * 16 + l15;
#pragma unroll
    for (int mt = 0; mt < 4; ++mt)
#pragma unroll
      for (int i = 0; i < 4; ++i) {
        const int row = r0 + wm * 64 + mt * 16 + quad * 4 + i;
        out[(size_t)row * 2048 + col] = acc[mt][nt][i];
      }
  }
}

// ---- merged projection dispatch: 0-31 E1-gemm, 32-159 xproj, 160-191 zero --
__global__ __launch_bounds__(256)
void k_proj(const float* __restrict__ emb, const float* __restrict__ Wr1,
            float* __restrict__ E1,
            const float* __restrict__ Wihf, const float* __restrict__ Wihb,
            float* __restrict__ Xf, float* __restrict__ Xb,
            float* __restrict__ cbuf, float* __restrict__ zm, float* __restrict__ zb)
{
  const int bid = blockIdx.x;
  if (bid < 32) {
    gemm_body(emb, Wr1, E1, bid & 3, bid >> 2);
  } else if (bid < 160) {
    const int idx = bid - 32;
    const int bz = idx >> 6, rem = idx & 63;
    xproj_body(emb, bz ? Wihb : Wihf, bz ? Xb : Xf, rem & 15, rem >> 4);
  } else {
    const int i0 = (bid - 160) * 256 + threadIdx.x;
    const int stride = 32 * 256;
    for (int k = i0; k < 49152; k += stride) cbuf[k] = 0.0f;
    for (int k = i0; k < 64; k += stride) zm[k] = 0.0f;
    for (int k = i0; k < 2048; k += stride) zb[k] = 0.0f;
  }
}

// ---- scan body (blocks 0-63 of k_scansc); Whh converted inline at preload --
__device__ void scan_body(const float* __restrict__ Xf, const float* __restrict__ Xb,
                          const float* __restrict__ Whhf,
                          const float* __restrict__ Whhb,
                          const float* __restrict__ bf, const float* __restrict__ bb,
                          const int* __restrict__ len,
                          unsigned short* __restrict__ hbB, float* __restrict__ cbuf,
                          float* __restrict__ hs, float* __restrict__ cs,
                          int* __restrict__ bar, int bid)
{
  const int dir = bid >> 5;
  const int hjt = bid & 31;
  const int tid = threadIdx.x;
  const int wave = tid >> 6, lane = tid & 63;
  const int l15 = lane & 15, quad = lane >> 4;
  const float* Wh = dir ? Whhb : Whhf;
  const float* bias = dir ? bb : bf;
  const float* X = dir ? Xb : Xf;
  int* myflags = &bar[528 + dir * 32];
  __shared__ float sg[4 * 16 * 17];
  const int jg = wave * 512 + hjt * 16 + l15;
  // time-invariant weight fragments, converted f32->bf16 once: 64 VGPRs
  short8 wfr[16];
#pragma unroll
  for (int k8 = 0; k8 < 16; ++k8) {
    const float* pw = &Wh[(size_t)jg * 512 + k8 * 32 + quad * 8];
    short8 w;
#pragma unroll
    for (int e = 0; e < 8; ++e) w[e] = (short)f2bf(pw[e]);
    wfr[k8] = w;
  }
  const int bb_ = tid >> 4, j = tid & 15;
  const int hj = hjt * 16 + j;
  const int Lb = len[bb_];
  const float bi_i = bias[hj];
  const float bi_f = bias[512 + hj];
  const float bi_g = bias[1024 + hj];
  const float bi_o = bias[1536 + hj];
  for (int t = 0; t < SL; ++t) {
    const int pp = t & 1;
    const unsigned short* hp = hbB + (size_t)(dir * 2 + pp) * 8192;
    unsigned short* hn = hbB + (size_t)(dir * 2 + (pp ^ 1)) * 8192;
    const float* cp = cbuf + (size_t)(dir * 2 + pp) * 8192;
    float* cn = cbuf + (size_t)(dir * 2 + (pp ^ 1)) * 8192;
    int xidx = t;
    if (dir) xidx = (t < Lb) ? (Lb - 1 - t) : t;
    const float* xr = X + (size_t)(bb_ * SL + xidx) * 2048;
    const float x0 = xr[hj];
    const float x1 = xr[512 + hj];
    const float x2 = xr[1024 + hj];
    const float x3 = xr[1536 + hj];
    const float cprev = cp[bb_ * 512 + hj];
    short8 afr[16];
#pragma unroll
    for (int k8 = 0; k8 < 16; ++k8)
      asm volatile("global_load_dwordx4 %0, %1, off sc0 sc1"
                   : "=&v"(afr[k8])
                   : "v"(&hp[(size_t)l15 * 512 + k8 * 32 + quad * 8]));
    asm volatile("s_waitcnt vmcnt(0)" ::: "memory");
    __builtin_amdgcn_sched_barrier(0);
    floatx4 acc = (floatx4){0.f, 0.f, 0.f, 0.f};
#pragma unroll
    for (int k8 = 0; k8 < 16; ++k8)
      acc = __builtin_amdgcn_mfma_f32_16x16x32_bf16(afr[k8], wfr[k8], acc, 0, 0, 0);
#pragma unroll
    for (int i = 0; i < 4; ++i)
      sg[wave * 272 + (quad * 4 + i) * 17 + l15] = acc[i];
    __syncthreads();
    const float gi = sg[0 * 272 + bb_ * 17 + j] + x0 + bi_i;
    const float gf = sg[1 * 272 + bb_ * 17 + j] + x1 + bi_f;
    const float gg = sg[2 * 272 + bb_ * 17 + j] + x2 + bi_g;
    const float go = sg[3 * 272 + bb_ * 17 + j] + x3 + bi_o;
    const float cnew = sigf(gf) * cprev + sigf(gi) * tanhf(gg);
    const float hnew = sigf(go) * tanhf(cnew);
    cn[bb_ * 512 + hj] = cnew;
    const unsigned int hb16 = f2bf(hnew);
    asm volatile("global_store_short %0, %1, off sc0 sc1"
                 :: "v"(&hn[bb_ * 512 + hj]), "v"(hb16) : "memory");
    const int pos = dir ? xidx : t;
    const int col = dir ? (512 + hj) : hj;
    hs[(size_t)(bb_ * SL + pos) * 1024 + col] = hnew;
    cs[(size_t)(bb_ * SL + pos) * 1024 + col] = cnew;
    if (t != SL - 1) bar32(myflags, hjt, t + 1);
  }
}

// ---- score body: ksplit stores sc-coherent; ALWAYS sets completion flag ----
__device__ void score_body(const float* __restrict__ E1, const float* __restrict__ Wr1,
                           const float* __restrict__ Wr2, const int* __restrict__ len,
                           int* __restrict__ ksplit, int* __restrict__ sflag,
                           int b, int s)
{
  const int tid = threadIdx.x;
  const int L = len[b];
  if (s + 2 <= L) {
    __shared__ float e[32 * 257];
    __shared__ float w1p[256];
    __shared__ float w2s[256];
    __shared__ float red[32 * 8];
    __shared__ float sc[32];
    const int nrow = 32 - s;
    for (int i = tid; i < nrow * 256; i += 256) {
      const int rr = i >> 8, q = i & 255;
      e[rr * 257 + q] = E1[(size_t)(b * SL + s + rr) * 256 + q];
    }
    w1p[tid] = Wr1[tid * 513 + 512];
    w2s[tid] = Wr2[tid];
    __syncthreads();
    const int t_ = tid & 31, jg = tid >> 5;
    const int lmax = L - s;
    for (int l = 2; l <= lmax; ++l) {
      float part = 0.0f;
      if (t_ < l) {
        const float pos = 2.0f * (float)t_ / (float)l - 1.0f;
        const float* er = e + t_ * 257;
        for (int q = jg * 32; q < jg * 32 + 32; ++q) {
          const float v = er[q] + pos * w1p[q];
          part += fmaxf(v, 0.0f) * w2s[q];
        }
      }
      red[t_ * 8 + jg] = part;
      __syncthreads();
      if (jg == 0 && t_ < l) {
        float su = 0.0f;
        for (int q = 0; q < 8; ++q) su += red[t_ * 8 + q];
        sc[t_] = su;
      }
      __syncthreads();
      if (tid == 0) {
        int k = 0;
        float best = sc[0];
        for (int q = 1; q < l; ++q)
          if (sc[q] > best) { best = sc[q]; k = q; }
        __hip_atomic_store(&ksplit[(b * 32 + s) * 33 + l], k,
                           __ATOMIC_RELAXED, __HIP_MEMORY_SCOPE_AGENT);
      }
      __syncthreads();
    }
  }
  __syncthreads();
  if (tid == 0) {
    asm volatile("s_waitcnt vmcnt(0)" ::: "memory");   // ksplit stores at L3
    __hip_atomic_store(&sflag[b * 31 + s], 1,
                       __ATOMIC_RELAXED, __HIP_MEMORY_SCOPE_AGENT);
  }
}

// ---- walk body: polls its sentence's 31 score flags, then DFS ----
__device__ void walk_body(const int* __restrict__ ksplit, const int* __restrict__ len,
                          int* __restrict__ meta, int* __restrict__ sflag, int b)
{
  const int tid = threadIdx.x;
  if (tid < 64) {
    int ok;
    do {
      int v = 1;
      if (tid < 31)
        v = __hip_atomic_load(&sflag[b * 31 + tid], __ATOMIC_RELAXED,
                              __HIP_MEMORY_SCOPE_AGENT);
      ok = (v != 0);
    } while (__all(ok) == 0);
  }
  __syncthreads();
  __shared__ int ks[32 * 33];
  __shared__ int stk[96];
  for (int i = tid; i < 32 * 33; i += 256)
    ks[i] = __hip_atomic_load(&ksplit[b * 1056 + i], __ATOMIC_RELAXED,
                              __HIP_MEMORY_SCOPE_AGENT);
  __syncthreads();
  if (tid != 0) return;
  int* own = meta;
  int* lt = meta + 512;
  int* li = meta + 1024;
  int* rt = meta + 1536;
  int* ri = meta + 2048;
  int* dep = meta + 2560;
  int* nn = meta + 3072;
  int* dcnt = meta + 3088;
  int* lcnt = meta + 3120;
  int* dlist = meta + 3152;
  int* llist = meta + 19536;
  int sp = 0, nn_ = 1;
  stk[0] = 0; stk[1] = len[b]; stk[2] = 0;
  sp = 1;
  while (sp > 0) {
    sp--;
    const int s = stk[sp * 3], eN = stk[sp * 3 + 1], nid = stk[sp * 3 + 2];
    const int l = eN - s;
    const int k = ks[s * 33 + l];
    const int m = b * 32 + nid;
    own[m] = s + k;
    if (k == 0) { lt[m] = 0; li[m] = 0; }
    else if (k == 1) { lt[m] = 1; li[m] = s; }
    else {
      const int id = nn_++;
      lt[m] = 2; li[m] = id;
      stk[sp * 3] = s; stk[sp * 3 + 1] = s + k; stk[sp * 3 + 2] = id; sp++;
    }
    const int rl = l - k - 1;
    if (rl == 0) { rt[m] = 0; ri[m] = 0; }
    else if (rl == 1) { rt[m] = 1; ri[m] = s + k + 1; }
    else {
      const int id = nn_++;
      rt[m] = 2; ri[m] = id;
      stk[sp * 3] = s + k + 1; stk[sp * 3 + 1] = eN; stk[sp * 3 + 2] = id; sp++;
    }
  }
  nn[b] = nn_;
  for (int i = nn_ - 1; i >= 0; --i) {
    const int m = b * 32 + i;
    int d = 1;
    if (lt[m] == 2) d = max(d, dep[b * 32 + li[m]] + 1);
    if (rt[m] == 2) d = max(d, dep[b * 32 + ri[m]] + 1);
    dep[m] = d;
  }
  for (int i = 0; i < nn_; ++i) {
    const int m = b * 32 + i;
    const int r = dep[m];
    const int idx = atomicAdd(&dcnt[r], 1);
    dlist[r * 512 + idx] = m;
    if (lt[m] == 2 || rt[m] == 2) {
      const int lx = atomicAdd(&lcnt[r], 1);
      llist[r * 512 + lx] = m;
    }
  }
}

// ---- merged scan+score+Wc-conv+walk dispatch ----
// blocks 0-63 scan, 64-559 score, 560-687 Wc f32->bf16 conversion (hidden
// under scan's idle CUs), 688-703 walk (polls score flags). All 704 blocks
// co-resident -> polls deadlock-free.
__global__ __launch_bounds__(256)
void k_scansc(const float* Xf, const float* Xb,
              const float* Whhf, const float* Whhb,
              const float* bf, const float* bb, const int* len,
              unsigned short* hbB, float* cbuf, float* hs, float* cs, int* bar,
              const float* E1, const float* Wr1, const float* Wr2, int* ksplit,
              const float* Wc, unsigned short* WcB, int* sflag, int* meta)
{
  const int bid = blockIdx.x;
  if (bid < 64) {
    scan_body(Xf, Xb, Whhf, Whhb, bf, bb, len, hbB, cbuf, hs, cs, bar, bid);
  } else if (bid < 560) {
    const int idx = bid - 64;
    score_body(E1, Wr1, Wr2, len, ksplit, sflag, idx / 31, idx % 31);
  } else if (bid < 688) {
    const int idx = bid - 560;
    const int nf4 = 15728640 >> 2;
    for (int i = idx * 256 + threadIdx.x; i < nf4; i += 128 * 256) {
      const float4 v = *(const float4*)&Wc[i * 4];
      ushort4 o;
      o.x = f2bf(v.x); o.y = f2bf(v.y); o.z = f2bf(v.z); o.w = f2bf(v.w);
      *(ushort4*)&WcB[i * 4] = o;
    }
  } else {
    walk_body(ksplit, len, meta, sflag, bid - 688);
  }
}

// ---------------- compose GEMM with INLINE U construction -------------------
// gB[r,g] = bc[g] + U[r,:] @ WcB[g,:]^T where U rows are built on the fly
// from hs + meta (hl-leaf | hr-leaf | hx), converted f32->bf16 in staging.
// Replaces k_ubuild + U buffer entirely.
__global__ __launch_bounds__(256)
void k_mfma_gemm(const float* __restrict__ hs, const int* __restrict__ meta,
                 const unsigned short* __restrict__ WcB,
                 const float* __restrict__ bc, float* __restrict__ gB)
{
  __shared__ __align__(16) unsigned short As[128 * 40];
  __shared__ __align__(16) unsigned short Bs[64 * 40];
  __shared__ const float* rowsrc[128][3];
  const int bid = blockIdx.x;
  const int r0 = (bid / 80) * 128;
  const int g0 = (bid % 80) * 64;
  const int tid = threadIdx.x;
  const int wave = tid >> 6, lane = tid & 63;
  const int wm = wave >> 1, wn = wave & 1;
  const int l15 = lane & 15, quad = lane >> 4;
  // per-row U-source pointers from meta (null -> zeros)
  if (tid < 128) {
    const int m = r0 + tid;
    const int b = m >> 5, id = m & 31;
    const int* lt = meta + 512;
    const int* li = meta + 1024;
    const int* rt = meta + 1536;
    const int* ri = meta + 2048;
    const int* own = meta;
    const int* nn = meta + 3072;
    const float* p0 = nullptr;
    const float* p1 = nullptr;
    const float* p2 = nullptr;
    if (id < nn[b]) {
      if (lt[m] == 1) p0 = hs + (size_t)(b * 32 + li[m]) * 1024;
      if (rt[m] == 1) p1 = hs + (size_t)(b * 32 + ri[m]) * 1024;
      p2 = hs + (size_t)(b * 32 + own[m]) * 1024;
    }
    rowsrc[tid][0] = p0;
    rowsrc[tid][1] = p1;
    rowsrc[tid][2] = p2;
  }
  floatx4 acc[4][2];
#pragma unroll
  for (int mf = 0; mf < 4; ++mf)
#pragma unroll
    for (int nt = 0; nt < 2; ++nt) acc[mf][nt] = (floatx4){0.f, 0.f, 0.f, 0.f};
  const int a_row = tid >> 2, a_q = tid & 3;
  for (int kt = 0; kt < K3; kt += 32) {
    __syncthreads();
#pragma unroll
    for (int p = 0; p < 2; ++p) {
      const int i = tid + p * 256;
      const int row = i >> 2, q = i & 3;
      const int kk = kt + q * 8;
      const int seg = kk >> 10, kl = kk & 1023;
      const float* sp = rowsrc[row][seg];
      ushort4 u0 = {0, 0, 0, 0}, u1 = {0, 0, 0, 0};
      if (sp) {
        const float4 a0 = *(const float4*)(sp + kl);
        const float4 a1 = *(const float4*)(sp + kl + 4);
        u0.x = f2bf(a0.x); u0.y = f2bf(a0.y); u0.z = f2bf(a0.z); u0.w = f2bf(a0.w);
        u1.x = f2bf(a1.x); u1.y = f2bf(a1.y); u1.z = f2bf(a1.z); u1.w = f2bf(a1.w);
      }
      *(ushort4*)&As[row * 40 + q * 8] = u0;
      *(ushort4*)&As[row * 40 + q * 8 + 4] = u1;
    }
    *(uint4*)&Bs[a_row * 40 + a_q * 8] = *(const uint4*)&WcB[(size_t)(g0 + a_row) * K3 + kt + a_q * 8];
    __syncthreads();
    short8 af[4], bfr[2];
#pragma unroll
    for (int mf = 0; mf < 4; ++mf)
      af[mf] = *(const short8*)&As[(wm * 64 + mf * 16 + l15) * 40 + quad * 8];
#pragma unroll
    for (int nt = 0; nt < 2; ++nt)
      bfr[nt] = *(const short8*)&Bs[(wn * 32 + nt * 16 + l15) * 40 + quad * 8];
#pragma unroll
    for (int mf = 0; mf < 4; ++mf)
#pragma unroll
      for (int nt = 0; nt < 2; ++nt)
        acc[mf][nt] = __builtin_amdgcn_mfma_f32_16x16x32_bf16(af[mf], bfr[nt], acc[mf][nt], 0, 0, 0);
  }
#pragma unroll
  for (int nt = 0; nt < 2; ++nt) {
    const int col = g0 + wn * 32 + nt * 16 + l15;
    const float bias = bc[col];
#pragma unroll
    for (int mf = 0; mf < 4; ++mf)
#pragma unroll
      for (int i = 0; i < 4; ++i) {
        const int row = r0 + wm * 64 + mf * 16 + quad * 4 + i;
        gB[(size_t)row * H5 + col] = acc[mf][nt][i] + bias;
      }
  }
}

// ---------------- fused tree rounds: hidden-index-partitioned ---------------
__global__ __launch_bounds__(256, 2)
void k_rounds(const unsigned short* __restrict__ WcB, const int* __restrict__ meta,
              unsigned short* __restrict__ nodehb,
              const float* __restrict__ gB, const float* __restrict__ cs,
              float* __restrict__ nodec,
              float* __restrict__ out, int* __restrict__ bar,
              const unsigned short* __restrict__ zpad)
{
  const int* lt = meta + 512;
  const int* li = meta + 1024;
  const int* rt = meta + 1536;
  const int* ri = meta + 2048;
  const int* dcnt = meta + 3088;
  const int* dlist = meta + 3152;
  __shared__ float scratch[4][16][17];
  __shared__ float gates[16][17];
  const int tid = threadIdx.x;
  const int bid = blockIdx.x;
  const int wave = tid >> 6, lane = tid & 63;
  const int l15 = lane & 15, quad = lane >> 4;
  const int j0 = bid * 2;
  const int cc = (l15 < 10) ? l15 : l15 - 10;
  const size_t wrow = (size_t)((cc >> 1) * 1024 + j0 + (cc & 1)) * K3;
  const int kbase = wave * 256 + quad * 8;
  short8 wreg[16];
#pragma unroll
  for (int i = 0; i < 8; ++i) {
    wreg[i]     = *(const short8*)&WcB[wrow + kbase + i * 32];
    wreg[8 + i] = *(const short8*)&WcB[wrow + 1024 + kbase + i * 32];
  }
  const int rnd = tid >> 4, rc = tid & 15;
  int bgen = 0;
  for (int r = 1; r <= 31; ++r) {
    const int cnt = dcnt[r];
    if (cnt == 0) break;
    if (r >= 2) { ++bgen; bar_rounds(bar, &bar[512], bid, bgen); }
    for (int c0 = 0; c0 < cnt; c0 += 16) {
      float gBv = 0.0f;
      if (rc < 10 && c0 + rnd < cnt) {
        const int nodeP = dlist[r * 512 + c0 + rnd];
        gBv = gB[(size_t)nodeP * H5 + (rc >> 1) * 1024 + j0 + (rc & 1)];
      }
      const int ma = c0 + l15;
      const unsigned short* pl = zpad;
      const unsigned short* pr = zpad;
      if (ma < cnt) {
        const int node = dlist[r * 512 + ma];
        const int base = node & ~31;
        if (lt[node] == 2) pl = nodehb + (size_t)(base + li[node]) * 1024;
        if (rt[node] == 2) pr = nodehb + (size_t)(base + ri[node]) * 1024;
      }
      short8 al[8], ar[8];
#pragma unroll
      for (int i = 0; i < 8; ++i)
        asm volatile("global_load_dwordx4 %0, %1, off sc0 sc1"
                     : "=&v"(al[i]) : "v"(pl + kbase + i * 32));
#pragma unroll
      for (int i = 0; i < 8; ++i)
        asm volatile("global_load_dwordx4 %0, %1, off sc0 sc1"
                     : "=&v"(ar[i]) : "v"(pr + kbase + i * 32));
      floatx4 acc = (floatx4){0.f, 0.f, 0.f, 0.f};
      asm volatile("s_waitcnt vmcnt(8)" ::: "memory");
      __builtin_amdgcn_sched_barrier(0);
#pragma unroll
      for (int ks = 0; ks < 8; ++ks)
        acc = __builtin_amdgcn_mfma_f32_16x16x32_bf16(al[ks], wreg[ks], acc, 0, 0, 0);
      asm volatile("s_waitcnt vmcnt(0)" ::: "memory");
      __builtin_amdgcn_sched_barrier(0);
#pragma unroll
      for (int ks = 0; ks < 8; ++ks)
        acc = __builtin_amdgcn_mfma_f32_16x16x32_bf16(ar[ks], wreg[8 + ks], acc, 0, 0, 0);
      __syncthreads();
#pragma unroll
      for (int i = 0; i < 4; ++i)
        scratch[wave][quad * 4 + i][l15] = acc[i];
      __syncthreads();
      if (rc < 10)
        gates[rnd][rc] = gBv + scratch[0][rnd][rc] + scratch[1][rnd][rc]
                             + scratch[2][rnd][rc] + scratch[3][rnd][rc];
      __syncthreads();
      if (tid < 16) {
        const int mc = c0 + tid;
        if (mc < cnt) {
          const int node = dlist[r * 512 + mc];
          const int base = node & ~31;
          const int ltv = lt[node], rtv = rt[node];
          const float* clp = (ltv == 2) ? &nodec[(size_t)(base + li[node]) * 1024]
                           : (ltv == 1) ? &cs[(size_t)(base + li[node]) * 1024] : nullptr;
          const float* crp = (rtv == 2) ? &nodec[(size_t)(base + ri[node]) * 1024]
                           : (rtv == 1) ? &cs[(size_t)(base + ri[node]) * 1024] : nullptr;
          unsigned int pk = 0;
#pragma unroll
          for (int jj = 0; jj < 2; ++jj) {
            const int j = j0 + jj;
            const float gi  = gates[tid][0 + jj];
            const float gfl = gates[tid][2 + jj];
            const float gfr = gates[tid][4 + jj];
            const float gu  = gates[tid][6 + jj];
            const float go  = gates[tid][8 + jj];
            const float cl = clp ? clp[j] : 0.0f;
            const float cr = crp ? crp[j] : 0.0f;
            const float c_ = sigf(gfl) * cl + sigf(gfr) * cr + sigf(gi) * tanhf(gu);
            const float h  = sigf(go) * tanhf(c_);
            nodec[(size_t)node * 1024 + j] = c_;
            pk |= ((unsigned int)f2bf(h)) << (16 * jj);
            if ((node & 31) == 0) {
              const int b = node >> 5;
              out[b * 1024 + j] = h;
              out[16384 + b * 1024 + j] = c_;
            }
          }
          asm volatile("global_store_dword %0, %1, off sc0 sc1"
                       :: "v"(nodehb + (size_t)node * 1024 + j0), "v"(pk)
                       : "memory");
        }
      }
    }
  }
}

extern "C" void kernel_launch(void* const* d_in, const int* in_sizes, int n_in,
                              void* d_out, int out_size, void* d_ws, size_t ws_size,
                              hipStream_t stream) {
  const float* emb = (const float*)d_in[0];
  const int* len = (const int*)d_in[1];
  const float* Wihf = (const float*)d_in[2];
  const float* Whhf = (const float*)d_in[3];
  const float* bf = (const float*)d_in[4];
  const float* Wihb = (const float*)d_in[5];
  const float* Whhb = (const float*)d_in[6];
  const float* bb = (const float*)d_in[7];
  const float* Wr1 = (const float*)d_in[8];
  const float* Wr2 = (const float*)d_in[9];
  const float* Wc = (const float*)d_in[10];
  const float* bc = (const float*)d_in[11];
  float* out = (float*)d_out;

  float* ws = (float*)d_ws;
  float* Xf = ws;                                         // 1048576 f
  float* Xb = Xf + 1048576;                               // 1048576 f
  float* hs = Xb + 1048576;                               // 524288 f
  float* cs = hs + 524288;                                // 524288 f
  float* E1 = cs + 524288;                                // 131072 f
  unsigned short* U = (unsigned short*)(E1 + 131072);     // (unused now)
  float* gB = (float*)U + 786432;                         // 2621440 f
  float* nodeh = gB + 2621440;                            // 524288 f (unused)
  float* nodec = nodeh + 524288;                          // 524288 f
  unsigned short* nodehb = (unsigned short*)(nodec + 524288);     // 262144 f
  float* cbuf = (float*)nodehb + 262144;                  // 32768 f
  unsigned short* hbB = (unsigned short*)(cbuf + 32768);  // 16384 f
  unsigned short* WcB = (unsigned short*)((float*)hbB + 16384);   // 7864320 f
  int* meta = (int*)(WcB + 15728640);                     // ~36K ints
  int* ksplit = meta + 36096;                             // 16*1056 ints
  int* bar = ksplit + 16896;                              // barrier state
  unsigned short* zpad = (unsigned short*)(bar + 1024);   // 1024 sh (512 int-eq)
  int* sflag = bar + 1536;                                // 512 ints score flags
  // bar layout: [0..511] rounds flags, [512] rounds gen,
  //             [528..559] scan flags dir0, [560..591] scan flags dir1

  // merged E1 gemm + input projections (inline f32->bf16) + state zeroing
  k_proj<<<192, 256, 0, stream>>>(emb, Wr1, E1, Wihf, Wihb, Xf, Xb,
                                  cbuf, (float*)(meta + 3088), (float*)bar);
  // merged recurrent scan (inline Whh conv) + scoring + Wc conv + DFS walk
  k_scansc<<<704, 256, 0, stream>>>(Xf, Xb, Whhf, Whhb, bf, bb, len, hbB,
                                    cbuf, hs, cs, bar, E1, Wr1, Wr2, ksplit,
                                    Wc, WcB, sflag, meta);
  // compose GEMM with inline U construction (replaces ubuild + mfma_gemm)
  k_mfma_gemm<<<320, 256, 0, stream>>>(hs, meta, WcB, bc, gB);
  // fused tree rounds (512 blocks, 1 monitor barrier/round)
  k_rounds<<<512, 256, 0, stream>>>(WcB, meta, nodehb, gB, cs,
                                    nodec, out, bar, zpad);
}